// Round 3
// baseline (2090.258 us; speedup 1.0000x reference)
//
#include <hip/hip_runtime.h>
#include <stdint.h>

#define EMB 64
#define BN_EPS 1e-5f
#define BKT 64            // nodes per bucket
#define TB_STRIDE 65

// ---------------- zero init (ws is poisoned 0xAA every call) ----------------
__global__ void k_zero(int* __restrict__ bcnt, float* __restrict__ stats,
                       int nb, int nstats) {
    int i = blockIdx.x * blockDim.x + threadIdx.x;
    if (i < nb) bcnt[i] = 0;
    if (i < nstats) stats[i] = 0.0f;
}

// ---------------- bucket histogram (LDS-combined) ----------------
__global__ void k_hist(const int* __restrict__ ei, int* __restrict__ bcnt,
                       int E, int nb) {
    extern __shared__ int lh[];
    for (int i = threadIdx.x; i < nb; i += blockDim.x) lh[i] = 0;
    __syncthreads();
    int stride = gridDim.x * blockDim.x;
    for (int e = blockIdx.x * blockDim.x + threadIdx.x; e < E; e += stride)
        atomicAdd(&lh[ei[E + e] >> 6], 1);
    __syncthreads();
    for (int i = threadIdx.x; i < nb; i += blockDim.x)
        if (lh[i]) atomicAdd(&bcnt[i], lh[i]);
}

// ---------------- single-block scan over buckets ----------------
__global__ void k_scan(const int* __restrict__ cnt, int* __restrict__ bstart,
                       int* __restrict__ bcur, int nb) {
    __shared__ int a[256];
    __shared__ int carry;
    int t = threadIdx.x;
    if (t == 0) carry = 0;
    __syncthreads();
    for (int base = 0; base < nb; base += 256) {
        int v = (base + t < nb) ? cnt[base + t] : 0;
        a[t] = v;
        __syncthreads();
        for (int off = 1; off < 256; off <<= 1) {
            int x = (t >= off) ? a[t - off] : 0;
            __syncthreads();
            a[t] += x;
            __syncthreads();
        }
        int excl = carry + (t ? a[t - 1] : 0);
        if (base + t < nb) { bstart[base + t] = excl; bcur[base + t] = excl; }
        __syncthreads();
        if (t == 0) carry += a[255];
        __syncthreads();
    }
    if (t == 0) bstart[nb] = carry;
}

// ---------------- XCD-grouped bucket scatter ----------------
// Blocks with blockIdx&7==g handle only buckets with b&7==g, so each pairs
// line is written by ONE XCD's L2 -> full-line writebacks (no 8x partial amp).
__global__ void k_scatter(const int* __restrict__ ei, const float* __restrict__ ew,
                          int* __restrict__ bcur, int2* __restrict__ pairs, int E) {
    const int group = blockIdx.x & 7;
    int e = (blockIdx.x >> 3) * blockDim.x + threadIdx.x;
    const int stride = (gridDim.x >> 3) * blockDim.x;
    for (; e < E; e += stride) {
        int dst = ei[E + e];
        int b = dst >> 6;
        if ((b & 7) == group) {
            int src = ei[e];
            float w = ew[e];
            int pos = atomicAdd(&bcur[b], 1);
            pairs[pos] = make_int2(src | ((dst & 63) << 26), __float_as_int(w));
        }
    }
}

// ---------------- aggregation: block per bucket, LDS accumulate ----------
__global__ void __launch_bounds__(256) k_agg(
        const float* __restrict__ h, const int* __restrict__ bstart,
        const int2* __restrict__ pairs, float* __restrict__ out, int N) {
    __shared__ float lacc[BKT * EMB];
    const int tid = threadIdx.x;
    const int lane = tid & 63;
    const int wid = tid >> 6;
    const int bucket = blockIdx.x;
    const int node0 = bucket << 6;
    float4* lacc4 = (float4*)lacc;
    for (int i = tid; i < BKT * EMB / 4; i += 256)
        lacc4[i] = make_float4(0.f, 0.f, 0.f, 0.f);
    __syncthreads();

    int e0 = bstart[bucket], e1 = bstart[bucket + 1];
    int cnt = e1 - e0;
    int per = (cnt + 3) >> 2;
    int ws = e0 + wid * per;
    int we = min(e1, ws + per);
    ws = __builtin_amdgcn_readfirstlane(ws);
    we = __builtin_amdgcn_readfirstlane(we);

    int e = ws;
    for (; e + 3 < we; e += 4) {
        int2 p0 = pairs[e], p1 = pairs[e + 1], p2 = pairs[e + 2], p3 = pairs[e + 3];
        unsigned x0 = p0.x, x1 = p1.x, x2 = p2.x, x3 = p3.x;
        float v0 = h[(size_t)(x0 & 0x3FFFFFFu) * EMB + lane];
        float v1 = h[(size_t)(x1 & 0x3FFFFFFu) * EMB + lane];
        float v2 = h[(size_t)(x2 & 0x3FFFFFFu) * EMB + lane];
        float v3 = h[(size_t)(x3 & 0x3FFFFFFu) * EMB + lane];
        atomicAdd(&lacc[(x0 >> 26) * EMB + lane], __int_as_float(p0.y) * v0);
        atomicAdd(&lacc[(x1 >> 26) * EMB + lane], __int_as_float(p1.y) * v1);
        atomicAdd(&lacc[(x2 >> 26) * EMB + lane], __int_as_float(p2.y) * v2);
        atomicAdd(&lacc[(x3 >> 26) * EMB + lane], __int_as_float(p3.y) * v3);
    }
    for (; e < we; e++) {
        int2 p = pairs[e];
        unsigned x = p.x;
        float v = h[(size_t)(x & 0x3FFFFFFu) * EMB + lane];
        atomicAdd(&lacc[(x >> 26) * EMB + lane], __int_as_float(p.y) * v);
    }
    __syncthreads();

    // out = lds_acc + h (self term); fully coalesced
    const float4* hb = (const float4*)(h + (size_t)node0 * EMB);
    float4* ob = (float4*)(out + (size_t)node0 * EMB);
    const int nvalid = min(BKT, N - node0);
    for (int i = tid; i < BKT * EMB / 4; i += 256) {
        int node = i >> 4;
        if (node < nvalid) {
            float4 a = lacc4[i];
            float4 hh = hb[i];
            ob[i] = make_float4(a.x + hh.x, a.y + hh.y, a.z + hh.z, a.w + hh.w);
        }
    }
}

// ---------------- matmul: wave = 64 nodes x 64 cols, fused BN-in + stats ----
template <bool BN_IN, bool DO_STATS>
__global__ void __launch_bounds__(128) k_mm(
                     const float* __restrict__ in, const float* __restrict__ W,
                     const float* __restrict__ bias, const float* __restrict__ stats,
                     const float* __restrict__ g, const float* __restrict__ be,
                     float invN, float* __restrict__ out, float* __restrict__ st_out,
                     int N) {
    __shared__ float tilebuf[2][64 * TB_STRIDE];
    __shared__ float st_part[128];
    const int tid = threadIdx.x;
    const int lane = tid & 63;
    float* tb = tilebuf[tid >> 6];
    if (DO_STATS) {
        st_part[tid] = 0.f;
        __syncthreads();
    }
    float s_sum = 0.f, s_sq = 0.f;

    int wv = (blockIdx.x * blockDim.x + tid) >> 6;
    const int nwv = (gridDim.x * blockDim.x) >> 6;
    const int ntiles = (N + 63) >> 6;
    for (int tile = wv; tile < ntiles; tile += nwv) {
        int utile = __builtin_amdgcn_readfirstlane(tile);
        int node = utile * 64 + lane;
        bool valid = node < N;

        float row[EMB];
        if (valid) {
            const float4* in4 = (const float4*)(in + (size_t)node * EMB);
#pragma unroll
            for (int i = 0; i < 16; i++) {
                float4 v = in4[i];
                row[4 * i + 0] = v.x; row[4 * i + 1] = v.y;
                row[4 * i + 2] = v.z; row[4 * i + 3] = v.w;
            }
        } else {
#pragma unroll
            for (int i = 0; i < EMB; i++) row[i] = 0.f;
        }

        if (BN_IN) {
#pragma unroll
            for (int f = 0; f < EMB; f++) {
                float m  = stats[f] * invN;
                float va = fmaf(stats[EMB + f], invN, -m * m);
                float rs = rsqrtf(va + BN_EPS);
                float sc = rs * g[f];
                float sh = fmaf(-m, sc, be[f]);
                row[f] = fmaxf(0.f, fmaf(row[f], sc, sh));
            }
        }

        for (int jc = 0; jc < 8; jc++) {
            int j0 = jc * 8;   // uniform
            float acc[8];
#pragma unroll
            for (int k = 0; k < 8; k++) acc[k] = bias[j0 + k];
#pragma unroll
            for (int f = 0; f < EMB; f++) {
                const float* wr = W + f * EMB + j0;   // uniform -> s_load
#pragma unroll
                for (int k = 0; k < 8; k++) acc[k] = fmaf(row[f], wr[k], acc[k]);
            }
#pragma unroll
            for (int k = 0; k < 8; k++)
                tb[lane * TB_STRIDE + j0 + k] = valid ? acc[k] : 0.f;
        }

        if (DO_STATS) {
            // lane = feature; walk the 64 nodes of this tile (conflict-free)
#pragma unroll 8
            for (int nn = 0; nn < 64; nn++) {
                float v = tb[nn * TB_STRIDE + lane];
                s_sum += v;
                s_sq = fmaf(v, v, s_sq);
            }
        }

        // flush: fully-coalesced float4 stores
        const int tbase = utile * 64;
        float4* out4 = (float4*)out + (size_t)tbase * 16;
#pragma unroll
        for (int it = 0; it < 16; it++) {
            int flat4 = it * 64 + lane;
            int nsub = flat4 >> 4;
            int c4 = flat4 & 15;
            if (tbase + nsub < N) {
                const float* s4 = tb + nsub * TB_STRIDE + c4 * 4;
                out4[flat4] = make_float4(s4[0], s4[1], s4[2], s4[3]);
            }
        }
    }

    if (DO_STATS) {
        atomicAdd(&st_part[lane], s_sum);
        atomicAdd(&st_part[64 + lane], s_sq);
        __syncthreads();
        if (tid < 128) atomicAdd(&st_out[tid], st_part[tid]);
    }
}

// ---------------- outer BN + relu + residual ----------------
__global__ void k_bnres(const float* __restrict__ u, const float* __restrict__ st,
                        const float* __restrict__ g, const float* __restrict__ be,
                        const float* __restrict__ hin, float* __restrict__ hout,
                        float invN, int total4) {
    int stride = gridDim.x * blockDim.x;
    for (int i4 = blockIdx.x * blockDim.x + threadIdx.x; i4 < total4; i4 += stride) {
        int c = i4 & 15;
        float4 uv = ((const float4*)u)[i4];
        float4 hv = ((const float4*)hin)[i4];
        float4 sv = ((const float4*)st)[c];
        float4 qv = ((const float4*)(st + EMB))[c];
        float4 gv = ((const float4*)g)[c];
        float4 bv = ((const float4*)be)[c];
        float4 o;
#define BNR(comp)                                                     \
        {                                                             \
            float m  = sv.comp * invN;                                \
            float va = fmaf(qv.comp, invN, -m * m);                   \
            float rs = rsqrtf(va + BN_EPS);                           \
            float sc = rs * gv.comp;                                  \
            float sh = fmaf(-m, sc, bv.comp);                         \
            float r  = fmaxf(0.f, fmaf(uv.comp, sc, sh));             \
            o.comp = r + hv.comp;                                     \
        }
        BNR(x) BNR(y) BNR(z) BNR(w)
#undef BNR
        ((float4*)hout)[i4] = o;
    }
}

// ---------------- launcher ----------------
extern "C" void kernel_launch(void* const* d_in, const int* in_sizes, int n_in,
                              void* d_out, int out_size, void* d_ws, size_t ws_size,
                              hipStream_t stream) {
    const float* x     = (const float*)d_in[0];
    const int*   ei    = (const int*)d_in[1];
    const float* ew    = (const float*)d_in[3];
    const float* ae_w  = (const float*)d_in[4];
    const float* ae_b  = (const float*)d_in[5];
    const float* W1    = (const float*)d_in[6];
    const float* b1    = (const float*)d_in[7];
    const float* g1    = (const float*)d_in[8];
    const float* be1   = (const float*)d_in[9];
    const float* W2    = (const float*)d_in[10];
    const float* b2    = (const float*)d_in[11];
    const float* g_out = (const float*)d_in[12];
    const float* be_out= (const float*)d_in[13];

    const int N = in_sizes[0] / EMB;
    const int E = in_sizes[3];
    const int L = in_sizes[6] / (EMB * EMB);
    const float invN = 1.0f / (float)N;
    const int NBUCK = (N + BKT - 1) / BKT;

    uintptr_t p = (uintptr_t)d_ws;
    auto alloc = [&](size_t bytes) -> void* {
        p = (p + 255) & ~(uintptr_t)255;
        void* r = (void*)p;
        p += bytes;
        return r;
    };
    float* h     = (float*)alloc((size_t)N * EMB * 4);
    float* bufa  = (float*)alloc((size_t)N * EMB * 4);
    float* buft  = (float*)alloc((size_t)N * EMB * 4);
    int*   bcnt  = (int*)alloc((size_t)NBUCK * 4);
    int*   bstart= (int*)alloc((size_t)(NBUCK + 1) * 4);
    int*   bcur  = (int*)alloc((size_t)NBUCK * 4);
    int2*  pairs = (int2*)alloc((size_t)E * 8);
    float* stats = (float*)alloc((size_t)L * 2 * 2 * EMB * 4);
    (void)ws_size; (void)n_in; (void)out_size;

    const int nstats = L * 2 * 2 * EMB;
    int zmax = NBUCK > nstats ? NBUCK : nstats;
    hipLaunchKernelGGL(k_zero, dim3((zmax + 255) / 256), dim3(256), 0, stream,
                       bcnt, stats, NBUCK, nstats);

    const int ntiles = (N + 63) / 64;
    const int mmgrid = (ntiles + 1) / 2;   // 2 waves/block, 1 tile/wave
    // encoder: h = x @ ae_w + ae_b
    hipLaunchKernelGGL((k_mm<false, false>), dim3(mmgrid), dim3(128), 0, stream,
                       x, ae_w, ae_b, (const float*)nullptr, (const float*)nullptr,
                       (const float*)nullptr, 0.f, h, (float*)nullptr, N);

    // bucket-CSR build
    hipLaunchKernelGGL(k_hist, dim3(120), dim3(256), NBUCK * 4, stream,
                       ei, bcnt, E, NBUCK);
    hipLaunchKernelGGL(k_scan, dim3(1), dim3(256), 0, stream,
                       bcnt, bstart, bcur, NBUCK);
    hipLaunchKernelGGL(k_scatter, dim3(256), dim3(256), 0, stream,
                       ei, ew, bcur, pairs, E);

    for (int l = 0; l < L; l++) {
        float* stats1 = stats + (size_t)(l * 2 + 0) * 2 * EMB;
        float* stats2 = stats + (size_t)(l * 2 + 1) * 2 * EMB;

        hipLaunchKernelGGL(k_agg, dim3(NBUCK), dim3(256), 0, stream,
                           h, bstart, pairs, bufa, N);
        // t = agg @ W1 + b1   (+stats1)
        hipLaunchKernelGGL((k_mm<false, true>), dim3(mmgrid), dim3(128), 0, stream,
                           bufa, W1 + (size_t)l * EMB * EMB, b1 + (size_t)l * EMB,
                           (const float*)nullptr, (const float*)nullptr,
                           (const float*)nullptr, 0.f, buft, stats1, N);
        // u = relu(bn1(t)) @ W2 + b2   (+stats2)
        hipLaunchKernelGGL((k_mm<true, true>), dim3(mmgrid), dim3(128), 0, stream,
                           buft, W2 + (size_t)l * EMB * EMB, b2 + (size_t)l * EMB,
                           stats1, g1 + (size_t)l * EMB, be1 + (size_t)l * EMB,
                           invN, bufa, stats2, N);
        // h = relu(bn2(u)) + h
        float* hout = (l == L - 1) ? (float*)d_out : h;
        hipLaunchKernelGGL(k_bnres, dim3(1024), dim3(256), 0, stream,
                           bufa, stats2, g_out + (size_t)l * EMB, be_out + (size_t)l * EMB,
                           h, hout, invN, N * 16);
    }
}

// Round 4
// 668.841 us; speedup vs baseline: 3.1252x; 3.1252x over previous
//
#include <hip/hip_runtime.h>
#include <stdint.h>

#define EMB 64
#define BN_EPS 1e-5f
#define TB_STRIDE 65

// ---------------- zero init (ws is poisoned 0xAA every call) ----------------
__global__ void k_zero(int* __restrict__ counts, float* __restrict__ stats,
                       int n, int nstats) {
    int i = blockIdx.x * blockDim.x + threadIdx.x;
    if (i < n) counts[i] = 0;
    if (i < nstats) stats[i] = 0.0f;
}

// ---------------- CSR build ----------------
__global__ void k_hist(const int* __restrict__ ei, int* __restrict__ counts, int E) {
    int stride = gridDim.x * blockDim.x;
    for (int e = blockIdx.x * blockDim.x + threadIdx.x; e < E; e += stride) {
        atomicAdd(&counts[ei[E + e]], 1);   // dst row
    }
}

__global__ void k_scanA(const int* __restrict__ counts, int* __restrict__ bsum, int n) {
    __shared__ int a[256];
    int t = threadIdx.x;
    int i = blockIdx.x * 256 + t;
    a[t] = (i < n) ? counts[i] : 0;
    __syncthreads();
    for (int off = 128; off >= 1; off >>= 1) {
        if (t < off) a[t] += a[t + off];
        __syncthreads();
    }
    if (t == 0) bsum[blockIdx.x] = a[0];
}

__global__ void k_scanB(int* __restrict__ bsum, int nb) {
    __shared__ int a[256];
    __shared__ int carry;
    int t = threadIdx.x;
    if (t == 0) carry = 0;
    __syncthreads();
    for (int base = 0; base < nb; base += 256) {
        int v = (base + t < nb) ? bsum[base + t] : 0;
        a[t] = v;
        __syncthreads();
        for (int off = 1; off < 256; off <<= 1) {
            int x = (t >= off) ? a[t - off] : 0;
            __syncthreads();
            a[t] += x;
            __syncthreads();
        }
        int excl = carry + (t ? a[t - 1] : 0);
        int tot  = carry + a[255];
        if (base + t < nb) bsum[base + t] = excl;   // in place: becomes block offsets
        __syncthreads();
        if (t == 0) carry = tot;
        __syncthreads();
    }
}

__global__ void k_scanC(const int* __restrict__ counts, const int* __restrict__ boff,
                        int* __restrict__ rowst, int* __restrict__ cursor, int n) {
    __shared__ int a[256];
    int t = threadIdx.x;
    int i = blockIdx.x * 256 + t;
    int v = (i < n) ? counts[i] : 0;
    a[t] = v;
    __syncthreads();
    for (int off = 1; off < 256; off <<= 1) {
        int x = (t >= off) ? a[t - off] : 0;
        __syncthreads();
        a[t] += x;
        __syncthreads();
    }
    int excl = boff[blockIdx.x] + (t ? a[t - 1] : 0);
    if (i < n) { rowst[i] = excl; cursor[i] = excl; }
}

// ---------------- XCD-grouped scatter ----------------
// Blocks with blockIdx&7==g handle only edges whose dst's 64-node bucket has
// (bucket&7)==g. The pairs region for a bucket (~16*64 edges = ~8KB) is then
// written by blocks of ONE XCD -> full-line writebacks, no 8x partial-line amp.
__global__ void k_scatter(const int* __restrict__ ei, const float* __restrict__ ew,
                          int* __restrict__ cursor, int2* __restrict__ pairs, int E) {
    const int group = blockIdx.x & 7;
    int e = (blockIdx.x >> 3) * blockDim.x + threadIdx.x;
    const int stride = (gridDim.x >> 3) * blockDim.x;
    for (; e < E; e += stride) {
        int d = ei[E + e];
        if (((d >> 6) & 7) == group) {
            int pos = atomicAdd(&cursor[d], 1);
            pairs[pos] = make_int2(ei[e], __float_as_int(ew[e]));
        }
    }
}

// ---------------- aggregation: wave-per-node, lane=feature ----------------
__global__ void k_agg(const float* __restrict__ h, const int* __restrict__ rowst,
                      const int* __restrict__ counts, const int2* __restrict__ pairs,
                      float* __restrict__ out, int N) {
    const int lane = threadIdx.x & 63;
    int wave = (blockIdx.x * blockDim.x + threadIdx.x) >> 6;
    const int nwaves = (gridDim.x * blockDim.x) >> 6;
    for (int node = wave; node < N; node += nwaves) {
        int un = __builtin_amdgcn_readfirstlane(node);
        int s = rowst[un];
        int c = counts[un];
        int end = s + c;
        float a0 = 0.f, a1 = 0.f, a2 = 0.f, a3 = 0.f;
        int e = s;
        for (; e + 3 < end; e += 4) {
            int2 p0 = pairs[e];
            int2 p1 = pairs[e + 1];
            int2 p2 = pairs[e + 2];
            int2 p3 = pairs[e + 3];
            float v0 = h[(size_t)p0.x * EMB + lane];
            float v1 = h[(size_t)p1.x * EMB + lane];
            float v2 = h[(size_t)p2.x * EMB + lane];
            float v3 = h[(size_t)p3.x * EMB + lane];
            a0 = fmaf(__int_as_float(p0.y), v0, a0);
            a1 = fmaf(__int_as_float(p1.y), v1, a1);
            a2 = fmaf(__int_as_float(p2.y), v2, a2);
            a3 = fmaf(__int_as_float(p3.y), v3, a3);
        }
        for (; e < end; e++) {
            int2 p0 = pairs[e];
            a0 = fmaf(__int_as_float(p0.y), h[(size_t)p0.x * EMB + lane], a0);
        }
        out[(size_t)un * EMB + lane] = ((a0 + a1) + (a2 + a3)) + h[(size_t)un * EMB + lane];
    }
}

// ---------------- matmul: wave = 64 nodes x 64 cols, fused BN-in + stats ----
// Results staged in padded LDS (stride 65) then flushed with fully-coalesced
// float4 stores. DO_STATS: per-feature sum/sumsq reduced from the LDS tile.
template <bool BN_IN, bool DO_STATS>
__global__ void __launch_bounds__(128) k_mm(
                     const float* __restrict__ in, const float* __restrict__ W,
                     const float* __restrict__ bias, const float* __restrict__ stats,
                     const float* __restrict__ g, const float* __restrict__ be,
                     float invN, float* __restrict__ out, float* __restrict__ st_out,
                     int N) {
    __shared__ float tilebuf[2][64 * TB_STRIDE];
    __shared__ float st_part[128];
    const int tid = threadIdx.x;
    const int lane = tid & 63;
    float* tb = tilebuf[tid >> 6];
    if (DO_STATS) {
        st_part[tid] = 0.f;
        __syncthreads();
    }
    float s_sum = 0.f, s_sq = 0.f;

    int wv = (blockIdx.x * blockDim.x + tid) >> 6;
    const int nwv = (gridDim.x * blockDim.x) >> 6;
    const int ntiles = (N + 63) >> 6;
    for (int tile = wv; tile < ntiles; tile += nwv) {
        int utile = __builtin_amdgcn_readfirstlane(tile);
        int node = utile * 64 + lane;
        bool valid = node < N;

        float row[EMB];
        if (valid) {
            const float4* in4 = (const float4*)(in + (size_t)node * EMB);
#pragma unroll
            for (int i = 0; i < 16; i++) {
                float4 v = in4[i];
                row[4 * i + 0] = v.x; row[4 * i + 1] = v.y;
                row[4 * i + 2] = v.z; row[4 * i + 3] = v.w;
            }
        } else {
#pragma unroll
            for (int i = 0; i < EMB; i++) row[i] = 0.f;
        }

        if (BN_IN) {
#pragma unroll
            for (int f = 0; f < EMB; f++) {
                float m  = stats[f] * invN;
                float va = fmaf(stats[EMB + f], invN, -m * m);
                float rs = rsqrtf(va + BN_EPS);
                float sc = rs * g[f];
                float sh = fmaf(-m, sc, be[f]);
                row[f] = fmaxf(0.f, fmaf(row[f], sc, sh));
            }
        }

        for (int jc = 0; jc < 8; jc++) {
            int j0 = jc * 8;   // uniform
            float acc[8];
#pragma unroll
            for (int k = 0; k < 8; k++) acc[k] = bias[j0 + k];
#pragma unroll
            for (int f = 0; f < EMB; f++) {
                const float* wr = W + f * EMB + j0;   // uniform -> s_load
#pragma unroll
                for (int k = 0; k < 8; k++) acc[k] = fmaf(row[f], wr[k], acc[k]);
            }
#pragma unroll
            for (int k = 0; k < 8; k++)
                tb[lane * TB_STRIDE + j0 + k] = valid ? acc[k] : 0.f;
        }

        if (DO_STATS) {
            // lane = feature; walk the 64 nodes of this tile (stride 65 -> conflict-free)
#pragma unroll 8
            for (int nn = 0; nn < 64; nn++) {
                float v = tb[nn * TB_STRIDE + lane];
                s_sum += v;
                s_sq = fmaf(v, v, s_sq);
            }
        }

        // flush: fully-coalesced float4 stores
        const int tbase = utile * 64;
        float4* out4 = (float4*)out + (size_t)tbase * 16;
#pragma unroll
        for (int it = 0; it < 16; it++) {
            int flat4 = it * 64 + lane;
            int nsub = flat4 >> 4;
            int c4 = flat4 & 15;
            if (tbase + nsub < N) {
                const float* s4 = tb + nsub * TB_STRIDE + c4 * 4;
                out4[flat4] = make_float4(s4[0], s4[1], s4[2], s4[3]);
            }
        }
    }

    if (DO_STATS) {
        atomicAdd(&st_part[lane], s_sum);
        atomicAdd(&st_part[64 + lane], s_sq);
        __syncthreads();
        if (tid < 128) atomicAdd(&st_out[tid], st_part[tid]);
    }
}

// ---------------- outer BN + relu + residual ----------------
__global__ void k_bnres(const float* __restrict__ u, const float* __restrict__ st,
                        const float* __restrict__ g, const float* __restrict__ be,
                        const float* __restrict__ hin, float* __restrict__ hout,
                        float invN, int total4) {
    int stride = gridDim.x * blockDim.x;
    for (int i4 = blockIdx.x * blockDim.x + threadIdx.x; i4 < total4; i4 += stride) {
        int c = i4 & 15;
        float4 uv = ((const float4*)u)[i4];
        float4 hv = ((const float4*)hin)[i4];
        float4 sv = ((const float4*)st)[c];
        float4 qv = ((const float4*)(st + EMB))[c];
        float4 gv = ((const float4*)g)[c];
        float4 bv = ((const float4*)be)[c];
        float4 o;
#define BNR(comp)                                                     \
        {                                                             \
            float m  = sv.comp * invN;                                \
            float va = fmaf(qv.comp, invN, -m * m);                   \
            float rs = rsqrtf(va + BN_EPS);                           \
            float sc = rs * gv.comp;                                  \
            float sh = fmaf(-m, sc, bv.comp);                         \
            float r  = fmaxf(0.f, fmaf(uv.comp, sc, sh));             \
            o.comp = r + hv.comp;                                     \
        }
        BNR(x) BNR(y) BNR(z) BNR(w)
#undef BNR
        ((float4*)hout)[i4] = o;
    }
}

// ---------------- launcher ----------------
extern "C" void kernel_launch(void* const* d_in, const int* in_sizes, int n_in,
                              void* d_out, int out_size, void* d_ws, size_t ws_size,
                              hipStream_t stream) {
    const float* x     = (const float*)d_in[0];
    const int*   ei    = (const int*)d_in[1];
    const float* ew    = (const float*)d_in[3];
    const float* ae_w  = (const float*)d_in[4];
    const float* ae_b  = (const float*)d_in[5];
    const float* W1    = (const float*)d_in[6];
    const float* b1    = (const float*)d_in[7];
    const float* g1    = (const float*)d_in[8];
    const float* be1   = (const float*)d_in[9];
    const float* W2    = (const float*)d_in[10];
    const float* b2    = (const float*)d_in[11];
    const float* g_out = (const float*)d_in[12];
    const float* be_out= (const float*)d_in[13];

    const int N = in_sizes[0] / EMB;
    const int E = in_sizes[3];
    const int L = in_sizes[6] / (EMB * EMB);
    const float invN = 1.0f / (float)N;

    uintptr_t p = (uintptr_t)d_ws;
    auto alloc = [&](size_t bytes) -> void* {
        p = (p + 255) & ~(uintptr_t)255;
        void* r = (void*)p;
        p += bytes;
        return r;
    };
    float* h     = (float*)alloc((size_t)N * EMB * 4);
    float* bufa  = (float*)alloc((size_t)N * EMB * 4);
    float* buft  = (float*)alloc((size_t)N * EMB * 4);
    int*   counts= (int*)alloc((size_t)N * 4);
    int*   rowst = (int*)alloc((size_t)N * 4);
    int*   cursor= (int*)alloc((size_t)N * 4);
    const int NB = (N + 255) / 256;
    int*   bsum  = (int*)alloc((size_t)NB * 4);
    int2*  pairs = (int2*)alloc((size_t)E * 8);
    float* stats = (float*)alloc((size_t)L * 2 * 2 * EMB * 4);
    (void)ws_size; (void)n_in; (void)out_size;

    const int nstats = L * 2 * 2 * EMB;
    int zgrid = ((N > nstats ? N : nstats) + 255) / 256;
    hipLaunchKernelGGL(k_zero, dim3(zgrid), dim3(256), 0, stream, counts, stats, N, nstats);

    const int ntiles = (N + 63) / 64;
    const int mmgrid = (ntiles + 1) / 2;   // 2 waves/block, 1 tile/wave
    // encoder: h = x @ ae_w + ae_b
    hipLaunchKernelGGL((k_mm<false, false>), dim3(mmgrid), dim3(128), 0, stream,
                       x, ae_w, ae_b, (const float*)nullptr, (const float*)nullptr,
                       (const float*)nullptr, 0.f, h, (float*)nullptr, N);

    // CSR build
    const int eg = (E + 255) / 256;
    hipLaunchKernelGGL(k_hist,  dim3(eg), dim3(256), 0, stream, ei, counts, E);
    hipLaunchKernelGGL(k_scanA, dim3(NB), dim3(256), 0, stream, counts, bsum, N);
    hipLaunchKernelGGL(k_scanB, dim3(1),  dim3(256), 0, stream, bsum, NB);
    hipLaunchKernelGGL(k_scanC, dim3(NB), dim3(256), 0, stream, counts, bsum, rowst, cursor, N);
    hipLaunchKernelGGL(k_scatter, dim3(512), dim3(256), 0, stream, ei, ew, cursor, pairs, E);

    for (int l = 0; l < L; l++) {
        float* stats1 = stats + (size_t)(l * 2 + 0) * 2 * EMB;
        float* stats2 = stats + (size_t)(l * 2 + 1) * 2 * EMB;

        // agg + self
        hipLaunchKernelGGL(k_agg, dim3(1024), dim3(256), 0, stream,
                           h, rowst, counts, pairs, bufa, N);
        // t = agg @ W1 + b1   (+stats1)
        hipLaunchKernelGGL((k_mm<false, true>), dim3(mmgrid), dim3(128), 0, stream,
                           bufa, W1 + (size_t)l * EMB * EMB, b1 + (size_t)l * EMB,
                           (const float*)nullptr, (const float*)nullptr,
                           (const float*)nullptr, 0.f, buft, stats1, N);
        // u = relu(bn1(t)) @ W2 + b2   (+stats2)
        hipLaunchKernelGGL((k_mm<true, true>), dim3(mmgrid), dim3(128), 0, stream,
                           buft, W2 + (size_t)l * EMB * EMB, b2 + (size_t)l * EMB,
                           stats1, g1 + (size_t)l * EMB, be1 + (size_t)l * EMB,
                           invN, bufa, stats2, N);
        // h = relu(bn2(u)) + h
        float* hout = (l == L - 1) ? (float*)d_out : h;
        hipLaunchKernelGGL(k_bnres, dim3(1024), dim3(256), 0, stream,
                           bufa, stats2, g_out + (size_t)l * EMB, be_out + (size_t)l * EMB,
                           h, hout, invN, N * 16);
    }
}